// Round 7
// baseline (128.561 us; speedup 1.0000x reference)
//
#include <hip/hip_runtime.h>

// Problem constants: B=32, C_IN=64, C_OUT=128, K=3, H=W=128
#define BATCH 32
#define CIN   64
#define COUT  128
#define HW    128
#define OW    126            // H-K+1
#define IMG4  508032         // float4s per batch-image of out (128*126*126/4)

typedef float f4 __attribute__((ext_vector_type(4)));

// ---- Kernel 1: xs[c,h,w] = sum_b x[b,c,h,w]; f4, 4 chains, nt loads ----
__global__ __launch_bounds__(256) void k_bsum(const float* __restrict__ x,
                                              float* __restrict__ xs) {
    const int i = blockIdx.x * blockDim.x + threadIdx.x;   // over 262144 f4s
    const f4* __restrict__ x4 = (const f4*)x;
    const size_t s4 = CIN * HW * HW / 4;                   // 262144 f4 per batch
    f4 a0 = __builtin_nontemporal_load(&x4[i]);
    f4 a1 = __builtin_nontemporal_load(&x4[s4 + i]);
    f4 a2 = __builtin_nontemporal_load(&x4[2 * s4 + i]);
    f4 a3 = __builtin_nontemporal_load(&x4[3 * s4 + i]);
    #pragma unroll
    for (int b = 4; b < BATCH; b += 4) {
        a0 += __builtin_nontemporal_load(&x4[(size_t)b * s4 + i]);
        a1 += __builtin_nontemporal_load(&x4[(size_t)(b + 1) * s4 + i]);
        a2 += __builtin_nontemporal_load(&x4[(size_t)(b + 2) * s4 + i]);
        a3 += __builtin_nontemporal_load(&x4[(size_t)(b + 3) * s4 + i]);
    }
    ((f4*)xs)[i] = (a0 + a1) + (a2 + a3);
}

// ---- Kernel 2: conv(xs, w) + bias -> out batch 0 ONLY ----
// x read directly from global (L2/L3-resident) into registers; only weights
// staged in LDS (wave-uniform b64 broadcasts). Tile: 8 rows x 32 cols x 8 oc.
// Grid (64 spatial, 16 ocg) = 1024 blocks = 4 blocks/CU (16 waves/CU).
// Thread: tx=tid&7 (4 px), ty=(tid>>3)&7 (row), og=tid>>6 (2 oc each).
#define OCT 8              // out channels per block
#define ICC 16             // input-channel chunk for weight staging

__global__ __launch_bounds__(256, 4) void k_conv(const float* __restrict__ xs,
                                                 const float* __restrict__ w,
                                                 const float* __restrict__ bias,
                                                 float* __restrict__ out) {
    __shared__ float lw[ICC * 9 * OCT];          // 1152 floats = 4.6 KB

    const int tid  = threadIdx.x;
    const int tile = blockIdx.x;                 // 0..63
    const int ocg  = blockIdx.y;                 // 0..15
    const int row0 = (tile >> 2) * 8;            // 0..120
    const int col0 = (tile & 3) * 32;            // 0,32,64,96
    const int oc0  = ocg * OCT;

    const int tx = tid & 7;
    const int ty = (tid >> 3) & 7;
    const int og = tid >> 6;                     // 0..3 (wave-uniform)

    const int irow = row0 + ty;                  // output row; input rows irow+ky
    const int icol = col0 + tx * 4;              // output col base
    const bool tail = (icol + 5) < HW;           // cols icol+4..5 loadable

    float acc[2][4] = {};                        // [oc][px]

    for (int ic0 = 0; ic0 < CIN; ic0 += ICC) {
        __syncthreads();                         // protect lw from prior readers
        // Stage weight chunk: [(icL*9 + t)*8 + o] <- w[(oc0+o)*576 + (ic0+icL)*9 + t]
        for (int s = tid; s < ICC * 9 * OCT; s += 256) {
            const int o = s & 7;
            const int r = s >> 3;                // icL*9 + t
            lw[s] = w[(oc0 + o) * (CIN * 9) + ic0 * 9 + r];
        }
        __syncthreads();

        #pragma unroll 2
        for (int icL = 0; icL < ICC; ++icL) {
            const float* xb0 = &xs[(((ic0 + icL) * HW) + irow) * HW + icol];
            #pragma unroll
            for (int ky = 0; ky < 3; ++ky) {
                const int gr = irow + ky;
                float xv[6];
                if (gr < HW) {
                    const float4 xa = *(const float4*)(xb0 + ky * HW);
                    xv[0] = xa.x; xv[1] = xa.y; xv[2] = xa.z; xv[3] = xa.w;
                    if (tail) {
                        const float2 xt = *(const float2*)(xb0 + ky * HW + 4);
                        xv[4] = xt.x; xv[5] = xt.y;
                    } else { xv[4] = 0.f; xv[5] = 0.f; }
                } else {
                    xv[0] = xv[1] = xv[2] = xv[3] = xv[4] = xv[5] = 0.f;
                }
                const float* wb = &lw[(icL * 9 + ky * 3) * OCT + og * 2];
                #pragma unroll
                for (int kx = 0; kx < 3; ++kx) {
                    const float2 wv = *(const float2*)(wb + kx * OCT);  // broadcast
                    const float wf[2] = {wv.x, wv.y};
                    #pragma unroll
                    for (int o = 0; o < 2; ++o)
                        #pragma unroll
                        for (int p = 0; p < 4; ++p)
                            acc[o][p] = fmaf(wf[o], xv[kx + p], acc[o][p]);
                }
            }
        }
    }

    // Bias + write batch 0 only (row pitch 126f -> float2 stores)
    if (irow < OW) {
        #pragma unroll
        for (int o = 0; o < 2; ++o) {
            const int oc = oc0 + og * 2 + o;
            const float bv = bias[oc];
            const float r0 = acc[o][0] + bv, r1 = acc[o][1] + bv;
            const float r2 = acc[o][2] + bv, r3 = acc[o][3] + bv;
            float* op = &out[((size_t)oc * OW + irow) * OW + icol];
            if (icol + 4 <= OW) {
                ((float2*)op)[0] = make_float2(r0, r1);
                ((float2*)op)[1] = make_float2(r2, r3);
            } else {                              // icol == 124: 2 cols left
                ((float2*)op)[0] = make_float2(r0, r1);
            }
        }
    }
}

// ---- Kernel 3: broadcast out[0] -> out[1..31] ----
// One f4 per thread: 1 load (amortized 31x) + 31 independent wide stores.
// 1985 blocks = ~7.8 blocks/CU -> store pipe stays full.
__global__ __launch_bounds__(256) void k_bcast(float* __restrict__ out) {
    f4* __restrict__ o4 = (f4*)out;
    const int r = blockIdx.x * 256 + threadIdx.x;
    if (r >= IMG4) return;
    const f4 v = o4[r];
    #pragma unroll
    for (int b = 1; b < BATCH; ++b)
        o4[(size_t)b * IMG4 + r] = v;
}

extern "C" void kernel_launch(void* const* d_in, const int* in_sizes, int n_in,
                              void* d_out, int out_size, void* d_ws, size_t ws_size,
                              hipStream_t stream) {
    const float* x    = (const float*)d_in[0];   // [32,64,128,128]
    const float* w    = (const float*)d_in[1];   // [128,64,3,3]
    const float* bias = (const float*)d_in[2];   // [128,1,1]
    float* out = (float*)d_out;                  // [32,128,126,126]
    float* xs  = (float*)d_ws;                   // [64,128,128] scratch (4 MB)

    k_bsum<<<dim3(CIN * HW * HW / 4 / 256), dim3(256), 0, stream>>>(x, xs);
    k_conv<<<dim3(64, 16), dim3(256), 0, stream>>>(xs, w, bias, out);
    k_bcast<<<dim3((IMG4 + 255) / 256), dim3(256), 0, stream>>>(out);
}